// Round 2
// baseline (148.522 us; speedup 1.0000x reference)
//
#include <hip/hip_runtime.h>

// Problem: B=8, F=16, N=2048
//   w[b,i,j] = exp(-beta^2 * min(p_i,p_j) * (n_i + n_j - 2*<x_i,x_j>))
//   p_i = exp(2*alpha*log(emb[b,4,i])),  n_i = sum_f emb[b,f,i]^2
// Output 134 MB fp32; fixed harness poison ~104 us; pure-write floor ~20.3 us
// (emb is 1 MB -> fully L2-resident, HBM reads ~0).
//
// R2: 128x128 tile, 8x8/thread: 141 us total (kernel ~37 us).
// R4: nt stores: neutral. R5: chunk-split + nt: write amplification -> REVERTED.
// R6: conflict-free linear ds_write staging (zero bank conflicts): 142 us.
// R7: symmetry (triangular grid + register-transposed stores): 144 us -> NEUTRAL.
//     Lesson: compute is NOT critical path; kernel is store-bound at ~4.5 TB/s
//     effective vs 6.6 TB/s fill rate. REVERTED.
// R8 (this): attack write-stream locality. TILE 32x1024 (512 thr, 4x16/thread):
//     each block writes 32 rows x 4KB contiguous (8x R6's 512B chunks);
//     consecutive blocks (jx=0,1) complete full 8KB rows in dispatch order.
//     Staging 66KB/block from L2-resident emb. LDS 75KB -> 2 blocks/CU, so
//     staging/compute of one block hides under the other's write drain.

#define BATCH 8
#define FDIM 16
#define NPT 2048
#define TI 32
#define TJ 1024
#define NTHREADS 512

__global__ __launch_bounds__(NTHREADS, 4) void qcd_aware_kernel(
    const float* __restrict__ emb,
    const float* __restrict__ alpha_p,
    const float* __restrict__ beta_p,
    float* __restrict__ out)
{
    __shared__ float Bs[FDIM][TJ];   // 64 KB
    __shared__ float Af[FDIM][TI];   // 2 KB
    __shared__ float nJ[TJ], qJ[TJ]; // 8 KB
    __shared__ float nI[TI], qI[TI]; // 256 B

    const int b  = blockIdx.z;
    const int i0 = blockIdx.y * TI;
    const int j0 = blockIdx.x * TJ;
    const int t  = threadIdx.x;

    const float* base = emb + (size_t)b * FDIM * NPT;

    // ---- stage Bs (16x1024) + Af (16x32), linear word order ----
    // Bs: thread t writes words {4t + 2048*g} -> stride-1 ds_write_b128,
    // conflict-free; per wave-instr the global side reads 1KB contiguous.
    {
        float* BsF = &Bs[0][0];
        #pragma unroll
        for (int g = 0; g < 8; ++g) {
            const int w = 4 * t + 2048 * g;   // word in [0, 16384)
            const int f = w >> 10;
            const int j = w & 1023;
            *(float4*)&BsF[w] = *(const float4*)(base + (size_t)f * NPT + j0 + j);
        }
        if (t < 128) {
            const int w = 4 * t;              // word in [0, 512)
            const int f = w >> 5;
            const int i = w & 31;
            *(float4*)(&Af[0][0] + w) = *(const float4*)(base + (size_t)f * NPT + i0 + i);
        }
    }
    __syncthreads();

    const float alpha2 = 2.0f * alpha_p[0];
    const float beta   = beta_p[0];
    // q = -beta^2 * log2(e) * p   (negative scale: min(p_i,p_j) -> max(q_i,q_j))
    const float qscale = -(beta * beta) * 1.4426950408889634f;

    // ---- per-edge precompute: squared norm + scaled pow-momentum ----
    {
        #pragma unroll
        for (int g = 0; g < 2; ++g) {
            const int c = t + NTHREADS * g;   // 2 cols per thread
            float s = 0.f;
            #pragma unroll
            for (int f = 0; f < FDIM; ++f) { float v = Bs[f][c]; s += v * v; }
            nJ[c] = s;
            qJ[c] = qscale * __expf(alpha2 * __logf(Bs[4][c]));
        }
        if (t < TI) {
            float s = 0.f;
            #pragma unroll
            for (int f = 0; f < FDIM; ++f) { float v = Af[f][t]; s += v * v; }
            nI[t] = s;
            qI[t] = qscale * __expf(alpha2 * __logf(Af[4][t]));
        }
    }
    __syncthreads();

    // ---- gram: wave w owns rows 4w..4w+3; lane covers cols tx4 + 256*g ----
    const int wv  = t >> 6;          // wave 0..7
    const int r0  = 4 * wv;          // row base 0..28
    const int tx4 = (t & 63) * 4;    // 0..252

    float acc[4][16] = {};           // [row][g*4+jj]
    #pragma unroll
    for (int f = 0; f < FDIM; ++f) {
        const float4 a = *(const float4*)&Af[f][r0];   // wave-uniform broadcast
        const float av[4] = {a.x, a.y, a.z, a.w};
        #pragma unroll
        for (int g = 0; g < 4; ++g) {
            const float4 bq = *(const float4*)&Bs[f][tx4 + 256 * g];
            const float bb[4] = {bq.x, bq.y, bq.z, bq.w};
            #pragma unroll
            for (int ii = 0; ii < 4; ++ii)
                #pragma unroll
                for (int jj = 0; jj < 4; ++jj)
                    acc[ii][g * 4 + jj] = fmaf(av[ii], bb[jj], acc[ii][g * 4 + jj]);
        }
    }

    // ---- epilogue + store: per g, per row -> 1KB-contiguous store instrs ----
    #pragma unroll
    for (int g = 0; g < 4; ++g) {
        const float4 njv = *(const float4*)&nJ[tx4 + 256 * g];
        const float4 qjv = *(const float4*)&qJ[tx4 + 256 * g];
        const float nj[4] = {njv.x, njv.y, njv.z, njv.w};
        const float qj[4] = {qjv.x, qjv.y, qjv.z, qjv.w};
        #pragma unroll
        for (int ii = 0; ii < 4; ++ii) {
            const float ni = nI[r0 + ii];
            const float qi = qI[r0 + ii];
            float4 wo;
            float* wp = (float*)&wo;
            #pragma unroll
            for (int jj = 0; jj < 4; ++jj) {
                const float d = fmaf(-2.0f, acc[ii][g * 4 + jj], ni + nj[jj]);
                // exponent = max(qi,qj)*d <= 0 -> raw v_exp_f32 safe
                wp[jj] = __builtin_amdgcn_exp2f(fmaxf(qi, qj[jj]) * d);
            }
            const size_t rowp = ((size_t)b * NPT + (size_t)(i0 + r0 + ii)) * NPT + j0;
            *(float4*)(out + rowp + tx4 + 256 * g) = wo;
        }
    }
}

extern "C" void kernel_launch(void* const* d_in, const int* in_sizes, int n_in,
                              void* d_out, int out_size, void* d_ws, size_t ws_size,
                              hipStream_t stream) {
    const float* emb     = (const float*)d_in[0];
    const float* alpha_p = (const float*)d_in[1];
    const float* beta_p  = (const float*)d_in[2];
    float* out = (float*)d_out;

    dim3 grid(NPT / TJ, NPT / TI, BATCH);   // 2 x 64 x 8 = 1024 blocks
    dim3 block(NTHREADS);
    qcd_aware_kernel<<<grid, block, 0, stream>>>(emb, alpha_p, beta_p, out);
}

// Round 3
// 141.646 us; speedup vs baseline: 1.0485x; 1.0485x over previous
//
#include <hip/hip_runtime.h>

// Problem: B=8, F=16, N=2048
//   w[b,i,j] = exp(-beta^2 * min(p_i,p_j) * (n_i + n_j - 2*<x_i,x_j>))
//   p_i = exp(2*alpha*log(emb[b,4,i])),  n_i = sum_f emb[b,f,i]^2
// Output 134 MB fp32; fixed harness poison ~104 us; pure-write floor ~20.3 us
// (emb is 1 MB -> fully L2-resident, HBM reads ~0).
//
// R2: 128x128 tile, 8x8/thread: 141 us total (kernel ~37 us).
// R4: nt stores neutral. R5: chunk-split + nt: write amplification -> REVERTED.
// R6: conflict-free linear ds_write staging (zero bank conflicts): 142.1 us. BEST.
// R7: symmetry (triangular + register-transposed stores): 143.9 -> compute NOT
//     the critical path; transposed 64B segments ate the savings. REVERTED.
// R8: 32x1024 tile for 4KB store contiguity: 148.5 -> DRAM store locality not
//     the limiter either (and 2 blocks/CU hurt). REVERTED.
// R9 (this): phase-lock theory. All 8 blocks/CU run compute-then-store in
//     lockstep -> ~12us compute burst (no stores) + ~20us store burst (idle
//     VALU). Split per-thread 8x8 tile into two column halves: full f-loop ->
//     epilogue -> store per half, so the write drain starts ~50% into the
//     block. Cost: As re-read per phase (+50% LDS reads, hidden under drain).

#define BATCH 8
#define FDIM 16
#define NPT 2048
#define TILE 128

__global__ __launch_bounds__(256, 4) void qcd_aware_kernel(
    const float* __restrict__ emb,
    const float* __restrict__ alpha_p,
    const float* __restrict__ beta_p,
    float* __restrict__ out)
{
    __shared__ float As[FDIM][TILE];
    __shared__ float Bs[FDIM][TILE];
    __shared__ float nI[TILE], nJ[TILE], qI[TILE], qJ[TILE];

    const int b  = blockIdx.z;
    const int i0 = blockIdx.y * TILE;
    const int j0 = blockIdx.x * TILE;
    const int tid = threadIdx.x;

    // ---- stage A (i-cols) and B (j-cols): 16x128 floats each ----
    // Linear word order: thread writes words {2*tid + 512*r} -> stride-1
    // ds_write_b64, zero bank conflicts. Each 64-lane wave covers exactly
    // one f-row (128 words): f = w>>7, i = w&127; global float2 coalesced.
    {
        float* AsF = &As[0][0];
        float* BsF = &Bs[0][0];
        const float* base = emb + (size_t)b * FDIM * NPT;
        #pragma unroll
        for (int r = 0; r < 4; ++r) {
            const int w = 2 * tid + 512 * r;     // word in [0, 2048)
            const int f = w >> 7;
            const int i = w & 127;
            *(float2*)&AsF[w] = *(const float2*)(base + (size_t)f * NPT + i0 + i);
            *(float2*)&BsF[w] = *(const float2*)(base + (size_t)f * NPT + j0 + i);
        }
    }
    __syncthreads();

    const float alpha2 = 2.0f * alpha_p[0];
    const float beta   = beta_p[0];
    // q = -beta^2 * log2(e) * p   (negative scale: min(p_i,p_j) -> max(q_i,q_j))
    const float qscale = -(beta * beta) * 1.4426950408889634f;

    // ---- per-edge precompute: squared norm + scaled pow-momentum ----
    {
        const int e = tid & 127;
        float s = 0.f;
        if (tid < TILE) {
            #pragma unroll
            for (int f = 0; f < FDIM; ++f) { float v = As[f][e]; s += v * v; }
            nI[e] = s;
            qI[e] = qscale * __expf(alpha2 * __logf(As[4][e]));
        } else {
            #pragma unroll
            for (int f = 0; f < FDIM; ++f) { float v = Bs[f][e]; s += v * v; }
            nJ[e] = s;
            qJ[e] = qscale * __expf(alpha2 * __logf(Bs[4][e]));
        }
    }
    __syncthreads();

    // ---- two phases: column half h; full gram -> epilogue -> store per half
    //      so stores start draining at ~50% of block lifetime ----
    const int tx4 = (tid & 15) * 4;   // 0..60
    const int ty4 = (tid >> 4) * 4;   // 0..60

    #pragma unroll
    for (int h = 0; h < 2; ++h) {
        const int cb = h * 64 + tx4;  // column base within tile

        float acc[8][4] = {};
        #pragma unroll
        for (int f = 0; f < FDIM; ++f) {
            const float4 a0 = *(const float4*)&As[f][ty4];
            const float4 a1 = *(const float4*)&As[f][ty4 + 64];
            const float4 bq = *(const float4*)&Bs[f][cb];
            const float av[8] = {a0.x, a0.y, a0.z, a0.w, a1.x, a1.y, a1.z, a1.w};
            const float bb[4] = {bq.x, bq.y, bq.z, bq.w};
            #pragma unroll
            for (int ii = 0; ii < 8; ++ii)
                #pragma unroll
                for (int jj = 0; jj < 4; ++jj)
                    acc[ii][jj] = fmaf(av[ii], bb[jj], acc[ii][jj]);
        }

        const float4 njv = *(const float4*)&nJ[cb];
        const float4 qjv = *(const float4*)&qJ[cb];
        const float nj[4] = {njv.x, njv.y, njv.z, njv.w};
        const float qj[4] = {qjv.x, qjv.y, qjv.z, qjv.w};

        #pragma unroll
        for (int r = 0; r < 8; ++r) {
            const int il = (r >> 2) * 64 + ty4 + (r & 3);
            const float ni = nI[il];
            const float qi = qI[il];
            float4 wo;
            float* wp = (float*)&wo;
            #pragma unroll
            for (int jj = 0; jj < 4; ++jj) {
                const float d = fmaf(-2.0f, acc[r][jj], ni + nj[jj]);
                // exponent = max(qi,qj)*d in [-24, 0] -> raw v_exp_f32 safe
                wp[jj] = __builtin_amdgcn_exp2f(fmaxf(qi, qj[jj]) * d);
            }
            const size_t rowp = ((size_t)b * NPT + (size_t)(i0 + il)) * NPT + j0;
            *(float4*)(out + rowp + cb) = wo;
        }
    }
}

extern "C" void kernel_launch(void* const* d_in, const int* in_sizes, int n_in,
                              void* d_out, int out_size, void* d_ws, size_t ws_size,
                              hipStream_t stream) {
    const float* emb     = (const float*)d_in[0];
    const float* alpha_p = (const float*)d_in[1];
    const float* beta_p  = (const float*)d_in[2];
    float* out = (float*)d_out;

    dim3 grid(NPT / TILE, NPT / TILE, BATCH);  // 16 x 16 x 8
    dim3 block(256);
    qcd_aware_kernel<<<grid, block, 0, stream>>>(emb, alpha_p, beta_p, out);
}